// Round 12
// baseline (221.912 us; speedup 1.0000x reference)
//
#include <hip/hip_runtime.h>

// Gaussian pyramid, 4 levels. Input (16,3,1024,1024) f32.
// Level0 copy fused into level-1 reduce. Level k+1 = replicate-pad-2 +
// separable 5x5, stride 2.
//
// R12 theory: kernel was VGPR-limited to ~16 waves/CU (>64 VGPR). Trade
// per-wave prefetch (32 VGPR of next-iter rows) for occupancy:
// __launch_bounds__(256,8) forces <=64 VGPR -> 32 waves/CU, 2x TLP.
// Edge handling stays remap-once (also makes copy data correct at edges:
// remapped B,C are exactly the lane's owned 8 floats).

struct Row { float4 A, B, C, D; };

template <int WIN>
__device__ __forceinline__ Row loadrow(const float* ip, int iy, int xb) {
    const float4* p = (const float4*)(ip + (size_t)iy * WIN + xb);
    Row r; r.A = p[0]; r.B = p[1]; r.C = p[2]; r.D = p[3];
    return r;
}

// In-place remap for replicate padding. left: window := [bcast(A.x), A, B, C];
// right: [B, C, D, bcast(D.w)]. After remap, interior wiring AND the copy
// slots (B, C) are correct for every lane.
__device__ __forceinline__ void remap(Row& w, bool l, bool r) {
    const float4 A = w.A, B = w.B, C = w.C, D = w.D;
    w.A.z = l ? A.x : (r ? B.z : A.z);
    w.A.w = l ? A.x : (r ? B.w : A.w);
    w.B.x = l ? A.x : (r ? C.x : B.x);
    w.B.y = l ? A.y : (r ? C.y : B.y);
    w.B.z = l ? A.z : (r ? C.z : B.z);
    w.B.w = l ? A.w : (r ? C.w : B.w);
    w.C.x = l ? B.x : (r ? D.x : C.x);
    w.C.y = l ? B.y : (r ? D.y : C.y);
    w.C.z = l ? B.z : (r ? D.z : C.z);
    w.C.w = l ? B.w : (r ? D.w : C.w);
    w.D.x = l ? C.x : (r ? D.w : D.x);
}

// Select-free horizontal 5-tap (stride-2 phase) on a remapped row.
__device__ __forceinline__ float4 hconv(const Row& w) {
    const float k0 = 0.0625f, k1 = 0.25f, k2 = 0.375f;
    float4 h;
    h.x = k0 * (w.A.z + w.B.z) + k1 * (w.A.w + w.B.y) + k2 * w.B.x;
    h.y = k0 * (w.B.x + w.C.x) + k1 * (w.B.y + w.B.w) + k2 * w.B.z;
    h.z = k0 * (w.B.z + w.C.z) + k1 * (w.B.w + w.C.y) + k2 * w.C.x;
    h.w = k0 * (w.C.x + w.D.x) + k1 * (w.C.y + w.C.w) + k2 * w.C.z;
    return h;
}

template <int R, int HIN, int WIN, bool FUSE>
__global__ __launch_bounds__(256, 8) void gpyr_slide(
        const float* __restrict__ in,
        float* __restrict__ out0,
        float* __restrict__ out1) {
    constexpr int HOUT = HIN / 2, WOUT = WIN / 2;
    const int tx = threadIdx.x, ty = threadIdx.y;
    const int ox0 = (blockIdx.x * blockDim.x + tx) * 4;
    const int Y0  = (blockIdx.y * blockDim.y + ty) * R;
    const int img = blockIdx.z;

    const bool left  = (ox0 == 0);
    const bool right = (2 * ox0 + 12 > WIN);
    int xb = 2 * ox0 - 4;
    if (left)  xb = 0;
    if (right) xb = WIN - 16;

    const float* ip = in + (size_t)img * HIN * WIN;
    float* o1 = out1 + (size_t)img * HOUT * WOUT;
    float* o0 = out0 + (size_t)img * HIN * WIN;

    // Prologue through minimal live registers (keep peak VGPR < 64):
    // rows 2Y0-2 and 2Y0-1 in flight together, then 2Y0.
    float4 hs0, hs1, hs2, qlo, qhi;
    {
        Row t0 = loadrow<WIN>(ip, max(2 * Y0 - 2, 0), xb);
        Row t1 = loadrow<WIN>(ip, max(2 * Y0 - 1, 0), xb);
        remap(t0, left, right);
        hs0 = hconv(t0);
        remap(t1, left, right);
        hs1 = hconv(t1);
        Row t2 = loadrow<WIN>(ip, 2 * Y0, xb);
        remap(t2, left, right);
        hs2 = hconv(t2);
        qlo = t2.B; qhi = t2.C;   // copy data for even input row 2*Y0
    }

    const float k0 = 0.0625f, k1 = 0.25f, k2 = 0.375f;

#pragma unroll
    for (int i = 0; i < R; ++i) {
        const int oy = Y0 + i;

        Row ra = loadrow<WIN>(ip, 2 * oy + 1, xb);                  // always < HIN
        Row rb = loadrow<WIN>(ip, min(2 * oy + 2, HIN - 1), xb);

        // even-row copy from saved regs (no dependence on the new loads)
        if (FUSE) {
            float* op = o0 + (size_t)(2 * oy) * WIN + 2 * ox0;
            *(float4*)(op)     = qlo;
            *(float4*)(op + 4) = qhi;
        }

        remap(ra, left, right);
        if (FUSE) {
            float* op1 = o0 + (size_t)(2 * oy + 1) * WIN + 2 * ox0;
            *(float4*)(op1)     = ra.B;
            *(float4*)(op1 + 4) = ra.C;
        }
        float4 ha = hconv(ra);

        remap(rb, left, right);
        float4 hb = hconv(rb);
        qlo = rb.B; qhi = rb.C;   // row 2*oy+2 = next iteration's even row

        float4 o;
        o.x = k0 * (hs0.x + hb.x) + k1 * (hs1.x + ha.x) + k2 * hs2.x;
        o.y = k0 * (hs0.y + hb.y) + k1 * (hs1.y + ha.y) + k2 * hs2.y;
        o.z = k0 * (hs0.z + hb.z) + k1 * (hs1.z + ha.z) + k2 * hs2.z;
        o.w = k0 * (hs0.w + hb.w) + k1 * (hs1.w + ha.w) + k2 * hs2.w;
        *(float4*)(o1 + (size_t)oy * WOUT + ox0) = o;

        hs0 = hs2; hs1 = ha; hs2 = hb;   // slide down 2 input rows
    }
}

extern "C" void kernel_launch(void* const* d_in, const int* in_sizes, int n_in,
                              void* d_out, int out_size, void* d_ws, size_t ws_size,
                              hipStream_t stream) {
    const float* im = (const float*)d_in[0];
    float* out = (float*)d_out;

    const int NC = 16 * 3;
    const size_t L0 = (size_t)NC * 1024 * 1024;
    const size_t L1 = (size_t)NC * 512 * 512;
    const size_t L2 = (size_t)NC * 256 * 256;

    float* out0 = out;
    float* out1 = out0 + L0;
    float* out2 = out1 + L1;
    float* out3 = out2 + L2;

    // Level 0+1 fused: 512x512 out, R=4 -> 3072 blocks (8+ blocks/CU feedable).
    {
        dim3 block(64, 4, 1);
        dim3 grid(2, 512 / (4 * 4), NC);       // (2, 32, 48) = 3072
        gpyr_slide<4, 1024, 1024, true><<<grid, block, 0, stream>>>(im, out0, out1);
    }
    // Level 2: 256x256 out, R=2 -> 1536 blocks.
    {
        dim3 block(64, 4, 1);
        dim3 grid(1, 256 / (4 * 2), NC);       // (1, 32, 48) = 1536
        gpyr_slide<2, 512, 512, false><<<grid, block, 0, stream>>>(out1, nullptr, out2);
    }
    // Level 3: 128x128 out, R=2 -> 384 blocks.
    {
        dim3 block(32, 8, 1);
        dim3 grid(1, 128 / (8 * 2), NC);       // (1, 8, 48) = 384
        gpyr_slide<2, 256, 256, false><<<grid, block, 0, stream>>>(out2, nullptr, out3);
    }
}